// Round 2
// baseline (392.351 us; speedup 1.0000x reference)
//
#include <hip/hip_runtime.h>

#define T_SEQ 2048
#define DIM   2048
#define NH    16
#define HD    128
#define KVR   512

typedef unsigned short ushort_t;
typedef __attribute__((ext_vector_type(8))) short   short8;
typedef __attribute__((ext_vector_type(8))) __bf16  bf16x8;
typedef __attribute__((ext_vector_type(4))) float   f32x4;
typedef __attribute__((ext_vector_type(4))) unsigned int u32x4;

union V8 { short8 s; bf16x8 b; u32x4 u; };

__device__ inline float b2f(ushort_t u) {
    union { unsigned u; float f; } x; x.u = ((unsigned)u) << 16; return x.f;
}
__device__ inline ushort_t f2b(float f) {
    union { float f; unsigned u; } x; x.f = f;
    unsigned r = x.u + 0x7FFFu + ((x.u >> 16) & 1u);
    return (ushort_t)(r >> 16);
}

// ---------------------------------------------------------------------------
// Generic NT GEMM: C[m,n] = sum_k A[m,k]*B[n,k].
// A: f32 or bf16 (A_BF16). B: f32 (weights). C: bf16 or f32 (OUT_F32).
// MFMA bf16, f32 accumulate. BM=BN=128, BK=64, 256 threads (4 waves).
// ---------------------------------------------------------------------------
template <bool A_BF16, bool OUT_F32>
__global__ __launch_bounds__(256) void gemm_nt(
    const void* __restrict__ Av, const float* __restrict__ B,
    void* __restrict__ Cv, int M, int N, int K)
{
    __shared__ __align__(16) char sA[128 * 64 * 2];
    __shared__ __align__(16) char sB[128 * 64 * 2];

    const int tid  = threadIdx.x;
    const int wave = tid >> 6;
    const int lane = tid & 63;
    const int l15  = lane & 15;
    const int l4   = lane >> 4;
    const int bm   = blockIdx.x * 128;
    const int bn   = blockIdx.y * 128;
    const int wm   = (wave >> 1) * 64;
    const int wn   = (wave & 1) * 64;

    f32x4 acc[4][4] = {};

    for (int k0 = 0; k0 < K; k0 += 64) {
        __syncthreads();
        #pragma unroll
        for (int c = 0; c < 4; ++c) {
            int chunk = c * 256 + tid;
            int row   = chunk >> 3;       // 8 chunks (of 8 elems) per 64-wide row
            int col8  = chunk & 7;
            V8 va, vb;
            if constexpr (A_BF16) {
                va.u = *(const u32x4*)((const ushort_t*)Av + (size_t)(bm + row) * K + k0 + col8 * 8);
            } else {
                const float* pa = (const float*)Av + (size_t)(bm + row) * K + k0 + col8 * 8;
                f32x4 a0 = *(const f32x4*)pa, a1 = *(const f32x4*)(pa + 4);
                #pragma unroll
                for (int e = 0; e < 4; ++e) { va.b[e] = (__bf16)a0[e]; va.b[e + 4] = (__bf16)a1[e]; }
            }
            {
                const float* pb = B + (size_t)(bn + row) * K + k0 + col8 * 8;
                f32x4 b0 = *(const f32x4*)pb, b1 = *(const f32x4*)(pb + 4);
                #pragma unroll
                for (int e = 0; e < 4; ++e) { vb.b[e] = (__bf16)b0[e]; vb.b[e + 4] = (__bf16)b1[e]; }
            }
            *(u32x4*)(sA + ((row * 128 + col8 * 16) ^ ((row & 7) << 4))) = va.u;
            *(u32x4*)(sB + ((row * 128 + col8 * 16) ^ ((row & 7) << 4))) = vb.u;
        }
        __syncthreads();
        #pragma unroll
        for (int kk = 0; kk < 2; ++kk) {
            V8 a[4], b[4];
            #pragma unroll
            for (int i = 0; i < 4; ++i) {
                int row = wm + i * 16 + l15;
                a[i].u = *(const u32x4*)(sA + ((row * 128 + kk * 64 + l4 * 16) ^ ((row & 7) << 4)));
                int col = wn + i * 16 + l15;
                b[i].u = *(const u32x4*)(sB + ((col * 128 + kk * 64 + l4 * 16) ^ ((col & 7) << 4)));
            }
            #pragma unroll
            for (int i = 0; i < 4; ++i)
                #pragma unroll
                for (int j = 0; j < 4; ++j)
                    acc[i][j] = __builtin_amdgcn_mfma_f32_16x16x32_bf16(a[i].b, b[j].b, acc[i][j], 0, 0, 0);
        }
    }

    #pragma unroll
    for (int i = 0; i < 4; ++i)
        #pragma unroll
        for (int j = 0; j < 4; ++j)
            #pragma unroll
            for (int r = 0; r < 4; ++r) {
                int rowg = bm + wm + i * 16 + l4 * 4 + r;
                int colg = bn + wn + j * 16 + l15;
                if constexpr (OUT_F32)
                    ((float*)Cv)[(size_t)rowg * N + colg] = acc[i][j][r];
                else
                    ((ushort_t*)Cv)[(size_t)rowg * N + colg] = f2b(acc[i][j][r]);
            }
}

// ---------------------------------------------------------------------------
// Fused RMSNorm + RoPE, in place on bf16 X; f32 weight & cos/sin tables.
// One block per position t. 256 threads = 16 heads x 16 lanes; lane owns 8 d.
// ---------------------------------------------------------------------------
__global__ __launch_bounds__(256) void norm_rope(
    ushort_t* __restrict__ X, const float* __restrict__ W,
    const float* __restrict__ FC, const float* __restrict__ FS,
    int row_stride)
{
    const int t   = blockIdx.x;
    const int tid = threadIdx.x;
    const int h   = tid >> 4;
    const int sub = tid & 15;

    ushort_t* p = X + (size_t)t * row_stride + h * HD + sub * 8;
    V8 v; v.u = *(const u32x4*)p;
    float f[8];
    #pragma unroll
    for (int e = 0; e < 8; ++e) f[e] = b2f((ushort_t)v.s[e]);

    float ss = 0.f;
    #pragma unroll
    for (int e = 0; e < 8; ++e) ss += f[e] * f[e];
    ss += __shfl_xor(ss, 1);
    ss += __shfl_xor(ss, 2);
    ss += __shfl_xor(ss, 4);
    ss += __shfl_xor(ss, 8);
    float inv = rsqrtf(ss * (1.0f / 128.0f) + 1e-6f);

    float outv[8];
    #pragma unroll
    for (int k = 0; k < 4; ++k) {
        float c  = FC[(size_t)t * 64 + sub * 4 + k];
        float s  = FS[(size_t)t * 64 + sub * 4 + k];
        float w0 = W[sub * 8 + 2 * k];
        float w1 = W[sub * 8 + 2 * k + 1];
        float re = f[2 * k] * inv * w0;
        float im = f[2 * k + 1] * inv * w1;
        outv[2 * k]     = re * c - im * s;
        outv[2 * k + 1] = re * s + im * c;
    }
    V8 o;
    #pragma unroll
    for (int e = 0; e < 8; ++e) o.s[e] = (short)f2b(outv[e]);
    *(u32x4*)p = o.u;
}

// ---------------------------------------------------------------------------
// Causal flash attention (all-bf16 intermediates). Block = (64 q-rows, head).
// 4 waves x 16 q-rows. KV tile 64. K row-major swizzled; V transposed
// d-major swizzled; P via per-wave swizzled LDS round trip.
// ---------------------------------------------------------------------------
__global__ __launch_bounds__(256) void attn_kernel(
    const ushort_t* __restrict__ Q,   // [T][DIM] normed+roped bf16
    const ushort_t* __restrict__ KV,  // [T][2*DIM]; K at h*HD, V at DIM+h*HD
    ushort_t* __restrict__ O)         // [T][DIM]
{
    const int qb   = blockIdx.x;
    const int h    = blockIdx.y;
    const int tid  = threadIdx.x;
    const int wave = tid >> 6;
    const int lane = tid & 63;
    const int l15  = lane & 15;
    const int l4   = lane >> 4;

    __shared__ __align__(16) char sK[64 * 256];
    __shared__ __align__(16) char sV[128 * 128];
    __shared__ __align__(16) char sP[4 * 16 * 128];

    const int q0   = qb * 64;
    const int qrow = q0 + wave * 16 + l15;

    V8 qf[4];
    #pragma unroll
    for (int kk = 0; kk < 4; ++kk)
        qf[kk].u = *(const u32x4*)(Q + (size_t)qrow * DIM + h * HD + kk * 32 + l4 * 8);

    f32x4 o[8] = {};
    float mrow[4], lrow[4];
    #pragma unroll
    for (int r = 0; r < 4; ++r) { mrow[r] = -1e30f; lrow[r] = 0.f; }

    const float scale = 0.08838834764831845f;  // 1/sqrt(128)
    char* sPw = sP + wave * (16 * 128);

    for (int tile = 0; tile <= qb; ++tile) {
        const int kv0 = tile * 64;
        __syncthreads();
        #pragma unroll
        for (int c = 0; c < 4; ++c) {
            int chunk = c * 256 + tid;
            int row   = chunk >> 4;
            int col8  = chunk & 15;
            const size_t gbase = (size_t)(kv0 + row) * (2 * DIM) + h * HD + col8 * 8;
            u32x4 vk = *(const u32x4*)(KV + gbase);
            *(u32x4*)(sK + ((row * 256 + col8 * 16) ^ ((row & 7) << 4))) = vk;
            V8 vv; vv.u = *(const u32x4*)(KV + gbase + DIM);
            #pragma unroll
            for (int e = 0; e < 8; ++e) {
                int d = col8 * 8 + e;
                *(ushort_t*)(sV + ((d * 128 + row * 2) ^ ((d & 7) << 4))) = (ushort_t)vv.s[e];
            }
        }
        __syncthreads();

        // S = Q K^T
        f32x4 sacc[4] = {};
        #pragma unroll
        for (int kk = 0; kk < 4; ++kk) {
            #pragma unroll
            for (int cb = 0; cb < 4; ++cb) {
                int krow = cb * 16 + l15;
                V8 kf; kf.u = *(const u32x4*)(sK + ((krow * 256 + kk * 64 + l4 * 16) ^ ((krow & 7) << 4)));
                sacc[cb] = __builtin_amdgcn_mfma_f32_16x16x32_bf16(qf[kk].b, kf.b, sacc[cb], 0, 0, 0);
            }
        }

        // scale + causal mask + online softmax
        float p[4][4];
        float rmax[4];
        #pragma unroll
        for (int r = 0; r < 4; ++r) rmax[r] = -1e30f;
        const int qgbase = q0 + wave * 16 + l4 * 4;
        #pragma unroll
        for (int cb = 0; cb < 4; ++cb) {
            int kvg = kv0 + cb * 16 + l15;
            #pragma unroll
            for (int r = 0; r < 4; ++r) {
                float s = sacc[cb][r] * scale;
                if (kvg > qgbase + r) s = -1e30f;
                p[cb][r] = s;
                rmax[r] = fmaxf(rmax[r], s);
            }
        }
        float corr[4];
        #pragma unroll
        for (int r = 0; r < 4; ++r) {
            float m = rmax[r];
            m = fmaxf(m, __shfl_xor(m, 1));
            m = fmaxf(m, __shfl_xor(m, 2));
            m = fmaxf(m, __shfl_xor(m, 4));
            m = fmaxf(m, __shfl_xor(m, 8));
            float mnew = fmaxf(mrow[r], m);
            corr[r] = __expf(mrow[r] - mnew);
            mrow[r] = mnew;
            float rs = 0.f;
            #pragma unroll
            for (int cb = 0; cb < 4; ++cb) {
                float e = __expf(p[cb][r] - mnew);
                p[cb][r] = e;
                rs += e;
            }
            rs += __shfl_xor(rs, 1);
            rs += __shfl_xor(rs, 2);
            rs += __shfl_xor(rs, 4);
            rs += __shfl_xor(rs, 8);
            lrow[r] = lrow[r] * corr[r] + rs;
        }

        // P -> per-wave LDS
        #pragma unroll
        for (int cb = 0; cb < 4; ++cb)
            #pragma unroll
            for (int r = 0; r < 4; ++r) {
                int row = l4 * 4 + r, col = cb * 16 + l15;
                *(ushort_t*)(sPw + ((row * 128 + col * 2) ^ ((row & 7) << 4))) = f2b(p[cb][r]);
            }

        // rescale O
        #pragma unroll
        for (int nb = 0; nb < 8; ++nb)
            #pragma unroll
            for (int r = 0; r < 4; ++r)
                o[nb][r] *= corr[r];

        // O += P V
        #pragma unroll
        for (int kk2 = 0; kk2 < 2; ++kk2) {
            V8 pf; pf.u = *(const u32x4*)(sPw + ((l15 * 128 + kk2 * 64 + l4 * 16) ^ ((l15 & 7) << 4)));
            #pragma unroll
            for (int nb = 0; nb < 8; ++nb) {
                int d = nb * 16 + l15;
                V8 vf; vf.u = *(const u32x4*)(sV + ((d * 128 + kk2 * 64 + l4 * 16) ^ ((d & 7) << 4)));
                o[nb] = __builtin_amdgcn_mfma_f32_16x16x32_bf16(pf.b, vf.b, o[nb], 0, 0, 0);
            }
        }
    }

    #pragma unroll
    for (int nb = 0; nb < 8; ++nb)
        #pragma unroll
        for (int r = 0; r < 4; ++r) {
            int qgr = q0 + wave * 16 + l4 * 4 + r;
            float val = o[nb][r] / lrow[r];
            O[(size_t)qgr * DIM + h * HD + nb * 16 + l15] = f2b(val);
        }
}

// ---------------------------------------------------------------------------
extern "C" void kernel_launch(void* const* d_in, const int* in_sizes, int n_in,
                              void* d_out, int out_size, void* d_ws, size_t ws_size,
                              hipStream_t stream)
{
    const float* x    = (const float*)d_in[0];
    const float* wq   = (const float*)d_in[1];
    const float* wkvd = (const float*)d_in[2];
    const float* wkvu = (const float*)d_in[3];
    const float* wo   = (const float*)d_in[4];
    const float* qnw  = (const float*)d_in[5];
    const float* knw  = (const float*)d_in[6];
    const float* fc   = (const float*)d_in[7];
    const float* fs   = (const float*)d_in[8];
    float* out = (float*)d_out;

    char* ws = (char*)d_ws;
    ushort_t* Qb  = (ushort_t*)(ws);                             // 2048*2048 bf16 = 8 MB
    ushort_t* lat = (ushort_t*)(ws + (size_t)8  * 1024 * 1024);  // 2048*512       = 2 MB
    ushort_t* kv  = (ushort_t*)(ws + (size_t)10 * 1024 * 1024);  // 2048*4096      = 16 MB
    ushort_t* att = (ushort_t*)(ws + (size_t)26 * 1024 * 1024);  // 2048*2048      = 8 MB

    dim3 blk(256);
    // xq = x . wq^T                  (f32 A, f32 B -> bf16 C)
    gemm_nt<false, false><<<dim3(16, 16), blk, 0, stream>>>(x, wq, Qb, 2048, 2048, 2048);
    // latent = x . w_kv_down^T
    gemm_nt<false, false><<<dim3(16, 4), blk, 0, stream>>>(x, wkvd, lat, 2048, 512, 2048);
    // kv = latent . w_kv_up^T        (bf16 A)
    gemm_nt<true, false><<<dim3(16, 32), blk, 0, stream>>>(lat, wkvu, kv, 2048, 4096, 512);
    // rmsnorm + rope (in place, bf16)
    norm_rope<<<dim3(2048), blk, 0, stream>>>(Qb, qnw, fc, fs, 2048);
    norm_rope<<<dim3(2048), blk, 0, stream>>>(kv, knw, fc, fs, 4096);
    // causal flash attention (bf16)
    attn_kernel<<<dim3(32, 16), blk, 0, stream>>>(Qb, kv, att);
    // y = att . wo^T                 (bf16 A -> f32 C)
    gemm_nt<true, true><<<dim3(16, 16), blk, 0, stream>>>(att, wo, out, 2048, 2048, 2048);
}

// Round 3
// 271.418 us; speedup vs baseline: 1.4456x; 1.4456x over previous
//
#include <hip/hip_runtime.h>

#define T_SEQ 2048
#define DIM   2048
#define NH    16
#define HD    128
#define KVR   512

typedef unsigned short ushort_t;
typedef __attribute__((ext_vector_type(8))) short   short8;
typedef __attribute__((ext_vector_type(8))) __bf16  bf16x8;
typedef __attribute__((ext_vector_type(4))) float   f32x4;
typedef __attribute__((ext_vector_type(4))) unsigned int u32x4;

union V8 { short8 s; bf16x8 b; u32x4 u; };

__device__ inline float b2f(ushort_t u) {
    union { unsigned u; float f; } x; x.u = ((unsigned)u) << 16; return x.f;
}
__device__ inline ushort_t f2b(float f) {
    union { float f; unsigned u; } x; x.f = f;
    unsigned r = x.u + 0x7FFFu + ((x.u >> 16) & 1u);
    return (ushort_t)(r >> 16);
}

// ---------------------------------------------------------------------------
// Generic NT GEMM: C[m,n] = sum_k A[m,k]*B[n,k].  (unchanged from round 2)
// ---------------------------------------------------------------------------
template <bool A_BF16, bool OUT_F32>
__global__ __launch_bounds__(256) void gemm_nt(
    const void* __restrict__ Av, const float* __restrict__ B,
    void* __restrict__ Cv, int M, int N, int K)
{
    __shared__ __align__(16) char sA[128 * 64 * 2];
    __shared__ __align__(16) char sB[128 * 64 * 2];

    const int tid  = threadIdx.x;
    const int wave = tid >> 6;
    const int lane = tid & 63;
    const int l15  = lane & 15;
    const int l4   = lane >> 4;
    const int bm   = blockIdx.x * 128;
    const int bn   = blockIdx.y * 128;
    const int wm   = (wave >> 1) * 64;
    const int wn   = (wave & 1) * 64;

    f32x4 acc[4][4] = {};

    for (int k0 = 0; k0 < K; k0 += 64) {
        __syncthreads();
        #pragma unroll
        for (int c = 0; c < 4; ++c) {
            int chunk = c * 256 + tid;
            int row   = chunk >> 3;
            int col8  = chunk & 7;
            V8 va, vb;
            if constexpr (A_BF16) {
                va.u = *(const u32x4*)((const ushort_t*)Av + (size_t)(bm + row) * K + k0 + col8 * 8);
            } else {
                const float* pa = (const float*)Av + (size_t)(bm + row) * K + k0 + col8 * 8;
                f32x4 a0 = *(const f32x4*)pa, a1 = *(const f32x4*)(pa + 4);
                #pragma unroll
                for (int e = 0; e < 4; ++e) { va.b[e] = (__bf16)a0[e]; va.b[e + 4] = (__bf16)a1[e]; }
            }
            {
                const float* pb = B + (size_t)(bn + row) * K + k0 + col8 * 8;
                f32x4 b0 = *(const f32x4*)pb, b1 = *(const f32x4*)(pb + 4);
                #pragma unroll
                for (int e = 0; e < 4; ++e) { vb.b[e] = (__bf16)b0[e]; vb.b[e + 4] = (__bf16)b1[e]; }
            }
            *(u32x4*)(sA + ((row * 128 + col8 * 16) ^ ((row & 7) << 4))) = va.u;
            *(u32x4*)(sB + ((row * 128 + col8 * 16) ^ ((row & 7) << 4))) = vb.u;
        }
        __syncthreads();
        #pragma unroll
        for (int kk = 0; kk < 2; ++kk) {
            V8 a[4], b[4];
            #pragma unroll
            for (int i = 0; i < 4; ++i) {
                int row = wm + i * 16 + l15;
                a[i].u = *(const u32x4*)(sA + ((row * 128 + kk * 64 + l4 * 16) ^ ((row & 7) << 4)));
                int col = wn + i * 16 + l15;
                b[i].u = *(const u32x4*)(sB + ((col * 128 + kk * 64 + l4 * 16) ^ ((col & 7) << 4)));
            }
            #pragma unroll
            for (int i = 0; i < 4; ++i)
                #pragma unroll
                for (int j = 0; j < 4; ++j)
                    acc[i][j] = __builtin_amdgcn_mfma_f32_16x16x32_bf16(a[i].b, b[j].b, acc[i][j], 0, 0, 0);
        }
    }

    #pragma unroll
    for (int i = 0; i < 4; ++i)
        #pragma unroll
        for (int j = 0; j < 4; ++j)
            #pragma unroll
            for (int r = 0; r < 4; ++r) {
                int rowg = bm + wm + i * 16 + l4 * 4 + r;
                int colg = bn + wn + j * 16 + l15;
                if constexpr (OUT_F32)
                    ((float*)Cv)[(size_t)rowg * N + colg] = acc[i][j][r];
                else
                    ((ushort_t*)Cv)[(size_t)rowg * N + colg] = f2b(acc[i][j][r]);
            }
}

// ---------------------------------------------------------------------------
// Fused RMSNorm + RoPE (unchanged from round 2)
// ---------------------------------------------------------------------------
__global__ __launch_bounds__(256) void norm_rope(
    ushort_t* __restrict__ X, const float* __restrict__ W,
    const float* __restrict__ FC, const float* __restrict__ FS,
    int row_stride)
{
    const int t   = blockIdx.x;
    const int tid = threadIdx.x;
    const int h   = tid >> 4;
    const int sub = tid & 15;

    ushort_t* p = X + (size_t)t * row_stride + h * HD + sub * 8;
    V8 v; v.u = *(const u32x4*)p;
    float f[8];
    #pragma unroll
    for (int e = 0; e < 8; ++e) f[e] = b2f((ushort_t)v.s[e]);

    float ss = 0.f;
    #pragma unroll
    for (int e = 0; e < 8; ++e) ss += f[e] * f[e];
    ss += __shfl_xor(ss, 1);
    ss += __shfl_xor(ss, 2);
    ss += __shfl_xor(ss, 4);
    ss += __shfl_xor(ss, 8);
    float inv = rsqrtf(ss * (1.0f / 128.0f) + 1e-6f);

    float outv[8];
    #pragma unroll
    for (int k = 0; k < 4; ++k) {
        float c  = FC[(size_t)t * 64 + sub * 4 + k];
        float s  = FS[(size_t)t * 64 + sub * 4 + k];
        float w0 = W[sub * 8 + 2 * k];
        float w1 = W[sub * 8 + 2 * k + 1];
        float re = f[2 * k] * inv * w0;
        float im = f[2 * k + 1] * inv * w1;
        outv[2 * k]     = re * c - im * s;
        outv[2 * k + 1] = re * s + im * c;
    }
    V8 o;
    #pragma unroll
    for (int e = 0; e < 8; ++e) o.s[e] = (short)f2b(outv[e]);
    *(u32x4*)p = o.u;
}

// ---------------------------------------------------------------------------
// Causal flash attention, rewritten:
//  - block = (pair p, head): processes q-tile p then q-tile 31-p => exactly
//    33 kv-tile iterations per block, 256 blocks, perfectly balanced.
//  - swapped QK^T (mfma(K,Q) -> S^T): softmax fully lane-local (q = lane&15),
//    P rebuilt in-register via shfl (no P LDS round trip).
//  - V staged transposed via coalesced u32 loads + vectorized swizzled
//    ds_write_b128 (conflict-free).
//  - K/V double-buffered; one barrier per tile; mask only on diagonal tile.
// ---------------------------------------------------------------------------
__global__ __launch_bounds__(256) void attn_kernel(
    const ushort_t* __restrict__ Q,   // [T][DIM] normed+roped bf16
    const ushort_t* __restrict__ KV,  // [T][2*DIM]; K at h*HD, V at DIM+h*HD
    ushort_t* __restrict__ O)         // [T][DIM]
{
    const int pairb = blockIdx.x;  // 0..15
    const int h     = blockIdx.y;  // 0..15
    const int tid   = threadIdx.x;
    const int wave  = tid >> 6;
    const int lane  = tid & 63;
    const int Qq    = lane & 15;   // q within wave's strip (softmax side)
    const int G     = lane >> 4;   // 16-lane group

    __shared__ __align__(16) char sK[2][64 * 256];   // [kv][d] swizzled
    __shared__ __align__(16) char sV[2][128 * 128];  // [d][kv] swizzled

    // staging index precompute (t-invariant)
    const int krow[4] = { (0*256 + tid) >> 4, (1*256 + tid) >> 4,
                          (2*256 + tid) >> 4, (3*256 + tid) >> 4 };
    const int kc8 = tid & 15;
    const int vd  = lane * 2;            // d pair base for V staging
    const int vkvb[2] = { 0 * 4 + wave, 1 * 4 + wave };  // kv-block (8 kv each)

    const float scale = 0.08838834764831845f;  // 1/sqrt(128)

    u32x4 kreg[4];
    unsigned vreg[2][8];

    #pragma unroll
    for (int phase = 0; phase < 2; ++phase) {
        const int jt  = phase ? (31 - pairb) : pairb;
        const int q0w = jt * 64 + wave * 16;

        // Q fragment (B-operand): lane: Q[q0w+Qq][kk*32 + G*8 + e]
        V8 qf[4];
        #pragma unroll
        for (int kk = 0; kk < 4; ++kk)
            qf[kk].u = *(const u32x4*)(Q + (size_t)(q0w + Qq) * DIM + h * HD + kk * 32 + G * 8);

        f32x4 o[8] = {};
        float mrow = -1e30f, lrow = 0.f;

        // ---- stage tile 0 into buf 0 ----
        {
            const int kv0 = 0;
            #pragma unroll
            for (int rr = 0; rr < 4; ++rr)
                kreg[rr] = *(const u32x4*)(KV + (size_t)(kv0 + krow[rr]) * (2 * DIM) + h * HD + kc8 * 8);
            #pragma unroll
            for (int rr = 0; rr < 2; ++rr)
                #pragma unroll
                for (int e = 0; e < 8; ++e)
                    vreg[rr][e] = *(const unsigned*)(KV + (size_t)(kv0 + vkvb[rr] * 8 + e) * (2 * DIM) + DIM + h * HD + vd);
            #pragma unroll
            for (int rr = 0; rr < 4; ++rr)
                *(u32x4*)(sK[0] + ((krow[rr] * 256 + kc8 * 16) ^ ((krow[rr] & 7) << 4))) = kreg[rr];
            #pragma unroll
            for (int rr = 0; rr < 2; ++rr) {
                V8 lo, hi;
                #pragma unroll
                for (int e = 0; e < 8; ++e) {
                    lo.s[e] = (short)(vreg[rr][e] & 0xFFFFu);
                    hi.s[e] = (short)(vreg[rr][e] >> 16);
                }
                *(u32x4*)(sV[0] + ((vd * 128 + vkvb[rr] * 16) ^ ((vd & 7) << 4)))       = lo.u;
                *(u32x4*)(sV[0] + (((vd + 1) * 128 + vkvb[rr] * 16) ^ (((vd + 1) & 7) << 4))) = hi.u;
            }
        }

        int cur = 0;
        for (int t = 0; t <= jt; ++t) {
            __syncthreads();  // buf[cur] visible to all

            const bool pf = (t < jt);
            if (pf) {  // issue next tile's global loads (latency hides under compute)
                const int kv0n = (t + 1) * 64;
                #pragma unroll
                for (int rr = 0; rr < 4; ++rr)
                    kreg[rr] = *(const u32x4*)(KV + (size_t)(kv0n + krow[rr]) * (2 * DIM) + h * HD + kc8 * 8);
                #pragma unroll
                for (int rr = 0; rr < 2; ++rr)
                    #pragma unroll
                    for (int e = 0; e < 8; ++e)
                        vreg[rr][e] = *(const unsigned*)(KV + (size_t)(kv0n + vkvb[rr] * 8 + e) * (2 * DIM) + DIM + h * HD + vd);
            }

            const int kv0 = t * 64;
            // ---- S^T = K Q^T : C[m=kv][n=q], lane: q=Qq, kv=cb*16+G*4+r ----
            f32x4 sacc[4] = {};
            #pragma unroll
            for (int kk = 0; kk < 4; ++kk) {
                #pragma unroll
                for (int cb = 0; cb < 4; ++cb) {
                    int row = cb * 16 + Qq;
                    V8 kf;
                    kf.u = *(const u32x4*)(sK[cur] + ((row * 256 + kk * 64 + G * 16) ^ ((row & 7) << 4)));
                    sacc[cb] = __builtin_amdgcn_mfma_f32_16x16x32_bf16(kf.b, qf[kk].b, sacc[cb], 0, 0, 0);
                }
            }

            // ---- softmax (lane-local in q = Qq) ----
            float p[4][4];
            float tmax = -3e38f;
            const int qg = q0w + Qq;
            #pragma unroll
            for (int cb = 0; cb < 4; ++cb)
                #pragma unroll
                for (int r = 0; r < 4; ++r) {
                    float s = sacc[cb][r] * scale;
                    if (t == jt) {
                        int kvg = kv0 + cb * 16 + G * 4 + r;
                        if (kvg > qg) s = -1e30f;
                    }
                    p[cb][r] = s;
                    tmax = fmaxf(tmax, s);
                }
            tmax = fmaxf(tmax, __shfl_xor(tmax, 16));
            tmax = fmaxf(tmax, __shfl_xor(tmax, 32));
            float mnew = fmaxf(mrow, tmax);
            float corr = __expf(mrow - mnew);
            mrow = mnew;
            float rs = 0.f;
            #pragma unroll
            for (int cb = 0; cb < 4; ++cb)
                #pragma unroll
                for (int r = 0; r < 4; ++r) {
                    float e = __expf(p[cb][r] - mnew);
                    p[cb][r] = e;
                    rs += e;
                }
            rs += __shfl_xor(rs, 16);
            rs += __shfl_xor(rs, 32);
            lrow = lrow * corr + rs;

            // pack P to bf16 pairs: pk[cb][j] = (p[cb][2j] lo, p[cb][2j+1] hi)
            unsigned pk[4][2];
            #pragma unroll
            for (int cb = 0; cb < 4; ++cb) {
                pk[cb][0] = (unsigned)f2b(p[cb][0]) | ((unsigned)f2b(p[cb][1]) << 16);
                pk[cb][1] = (unsigned)f2b(p[cb][2]) | ((unsigned)f2b(p[cb][3]) << 16);
            }

            // rescale O: corr for q-row (G*4+r) fetched from lane l15=G*4+r
            float cf[4];
            #pragma unroll
            for (int r = 0; r < 4; ++r)
                cf[r] = __shfl(corr, G * 4 + r);
            #pragma unroll
            for (int nb = 0; nb < 8; ++nb)
                #pragma unroll
                for (int r = 0; r < 4; ++r)
                    o[nb][r] *= cf[r];

            // ---- O += P V : rebuild P A-fragment in-register ----
            const int sLo = ((G & 1) * 2) * 16 + Qq;
            const int sHi = sLo + 16;
            const bool hiC = (G >> 1);
            #pragma unroll
            for (int kk2 = 0; kk2 < 2; ++kk2) {
                const int c0 = kk2 * 2, c1 = c0 + 1;
                unsigned w0a = __shfl(pk[c0][0], sLo), w0b = __shfl(pk[c1][0], sLo);
                unsigned w1a = __shfl(pk[c0][1], sLo), w1b = __shfl(pk[c1][1], sLo);
                unsigned w2a = __shfl(pk[c0][0], sHi), w2b = __shfl(pk[c1][0], sHi);
                unsigned w3a = __shfl(pk[c0][1], sHi), w3b = __shfl(pk[c1][1], sHi);
                V8 pa;
                pa.u[0] = hiC ? w0b : w0a;
                pa.u[1] = hiC ? w1b : w1a;
                pa.u[2] = hiC ? w2b : w2a;
                pa.u[3] = hiC ? w3b : w3a;
                #pragma unroll
                for (int nb = 0; nb < 8; ++nb) {
                    int d = nb * 16 + Qq;
                    V8 vf;
                    vf.u = *(const u32x4*)(sV[cur] + ((d * 128 + kk2 * 64 + G * 16) ^ ((d & 7) << 4)));
                    o[nb] = __builtin_amdgcn_mfma_f32_16x16x32_bf16(pa.b, vf.b, o[nb], 0, 0, 0);
                }
            }

            // ---- write prefetched tile into other buffer ----
            if (pf) {
                #pragma unroll
                for (int rr = 0; rr < 4; ++rr)
                    *(u32x4*)(sK[cur ^ 1] + ((krow[rr] * 256 + kc8 * 16) ^ ((krow[rr] & 7) << 4))) = kreg[rr];
                #pragma unroll
                for (int rr = 0; rr < 2; ++rr) {
                    V8 lo, hi;
                    #pragma unroll
                    for (int e = 0; e < 8; ++e) {
                        lo.s[e] = (short)(vreg[rr][e] & 0xFFFFu);
                        hi.s[e] = (short)(vreg[rr][e] >> 16);
                    }
                    *(u32x4*)(sV[cur ^ 1] + ((vd * 128 + vkvb[rr] * 16) ^ ((vd & 7) << 4)))             = lo.u;
                    *(u32x4*)(sV[cur ^ 1] + (((vd + 1) * 128 + vkvb[rr] * 16) ^ (((vd + 1) & 7) << 4))) = hi.u;
                }
            }
            cur ^= 1;
        }

        // ---- epilogue: O /= l, store; output q-row = G*4+r ----
        float linv[4];
        #pragma unroll
        for (int r = 0; r < 4; ++r)
            linv[r] = 1.f / __shfl(lrow, G * 4 + r);
        #pragma unroll
        for (int nb = 0; nb < 8; ++nb)
            #pragma unroll
            for (int r = 0; r < 4; ++r) {
                int qgr = jt * 64 + wave * 16 + G * 4 + r;
                O[(size_t)qgr * DIM + h * HD + nb * 16 + Qq] = f2b(o[nb][r] * linv[r]);
            }

        __syncthreads();  // phase seam: no wave may still read LDS when next phase stages
    }
}

// ---------------------------------------------------------------------------
extern "C" void kernel_launch(void* const* d_in, const int* in_sizes, int n_in,
                              void* d_out, int out_size, void* d_ws, size_t ws_size,
                              hipStream_t stream)
{
    const float* x    = (const float*)d_in[0];
    const float* wq   = (const float*)d_in[1];
    const float* wkvd = (const float*)d_in[2];
    const float* wkvu = (const float*)d_in[3];
    const float* wo   = (const float*)d_in[4];
    const float* qnw  = (const float*)d_in[5];
    const float* knw  = (const float*)d_in[6];
    const float* fc   = (const float*)d_in[7];
    const float* fs   = (const float*)d_in[8];
    float* out = (float*)d_out;

    char* ws = (char*)d_ws;
    ushort_t* Qb  = (ushort_t*)(ws);                             // 2048*2048 bf16 = 8 MB
    ushort_t* lat = (ushort_t*)(ws + (size_t)8  * 1024 * 1024);  // 2048*512       = 2 MB
    ushort_t* kv  = (ushort_t*)(ws + (size_t)10 * 1024 * 1024);  // 2048*4096      = 16 MB
    ushort_t* att = (ushort_t*)(ws + (size_t)26 * 1024 * 1024);  // 2048*2048      = 8 MB

    dim3 blk(256);
    gemm_nt<false, false><<<dim3(16, 16), blk, 0, stream>>>(x, wq, Qb, 2048, 2048, 2048);
    gemm_nt<false, false><<<dim3(16, 4), blk, 0, stream>>>(x, wkvd, lat, 2048, 512, 2048);
    gemm_nt<true, false><<<dim3(16, 32), blk, 0, stream>>>(lat, wkvu, kv, 2048, 4096, 512);
    norm_rope<<<dim3(2048), blk, 0, stream>>>(Qb, qnw, fc, fs, 2048);
    norm_rope<<<dim3(2048), blk, 0, stream>>>(kv, knw, fc, fs, 4096);
    attn_kernel<<<dim3(16, 16), blk, 0, stream>>>(Qb, kv, att);
    gemm_nt<true, true><<<dim3(16, 16), blk, 0, stream>>>(att, wo, out, 2048, 2048, 2048);
}

// Round 4
// 197.644 us; speedup vs baseline: 1.9851x; 1.3733x over previous
//
#include <hip/hip_runtime.h>

#define T_SEQ 2048
#define DIM   2048
#define NH    16
#define HD    128
#define KVR   512

typedef unsigned short ushort_t;
typedef __attribute__((ext_vector_type(8))) short   short8;
typedef __attribute__((ext_vector_type(8))) __bf16  bf16x8;
typedef __attribute__((ext_vector_type(4))) float   f32x4;
typedef __attribute__((ext_vector_type(4))) unsigned int u32x4;

union V8 { short8 s; bf16x8 b; u32x4 u; };

__device__ inline float b2f(ushort_t u) {
    union { unsigned u; float f; } x; x.u = ((unsigned)u) << 16; return x.f;
}
__device__ inline ushort_t f2b(float f) {
    union { float f; unsigned u; } x; x.f = f;
    unsigned r = x.u + 0x7FFFu + ((x.u >> 16) & 1u);
    return (ushort_t)(r >> 16);
}

// ---------------------------------------------------------------------------
// Generic NT GEMM: C[m,n] = sum_k A[m,k]*B[n,k]. 8 waves (512 thr), wave grid
// 2x4, each wave 64x32 out. Optional fused second output: for bn >= Nsplit
// use B2/C2 (ldC = N2). A: f32 or bf16. B: f32. C: bf16 or f32.
// ---------------------------------------------------------------------------
template <bool A_BF16, bool OUT_F32>
__global__ __launch_bounds__(512) void gemm_nt(
    const void* __restrict__ Av, const float* __restrict__ B,
    void* __restrict__ Cv, int M, int K,
    const float* __restrict__ B2, void* __restrict__ C2, int Nsplit, int N2)
{
    __shared__ __align__(16) char sA[128 * 64 * 2];
    __shared__ __align__(16) char sB[128 * 64 * 2];

    const int tid  = threadIdx.x;
    const int wave = tid >> 6;
    const int lane = tid & 63;
    const int l15  = lane & 15;
    const int l4   = lane >> 4;
    const int bm   = blockIdx.x * 128;
    const int bn   = blockIdx.y * 128;

    const float* Bp = B;
    void*        Cp = Cv;
    int ldC = Nsplit;
    int bnl = bn;
    if (B2 != nullptr && bn >= Nsplit) { Bp = B2; Cp = C2; ldC = N2; bnl = bn - Nsplit; }

    const int wm = (wave >> 2) * 64;
    const int wn = (wave & 3) * 32;

    f32x4 acc[4][2] = {};

    for (int k0 = 0; k0 < K; k0 += 64) {
        __syncthreads();
        #pragma unroll
        for (int c = 0; c < 2; ++c) {
            int chunk = c * 512 + tid;
            int row   = chunk >> 3;
            int col8  = chunk & 7;
            V8 va, vb;
            if constexpr (A_BF16) {
                va.u = *(const u32x4*)((const ushort_t*)Av + (size_t)(bm + row) * K + k0 + col8 * 8);
            } else {
                const float* pa = (const float*)Av + (size_t)(bm + row) * K + k0 + col8 * 8;
                f32x4 a0 = *(const f32x4*)pa, a1 = *(const f32x4*)(pa + 4);
                #pragma unroll
                for (int e = 0; e < 4; ++e) { va.b[e] = (__bf16)a0[e]; va.b[e + 4] = (__bf16)a1[e]; }
            }
            {
                const float* pb = Bp + (size_t)(bnl + row) * K + k0 + col8 * 8;
                f32x4 b0 = *(const f32x4*)pb, b1 = *(const f32x4*)(pb + 4);
                #pragma unroll
                for (int e = 0; e < 4; ++e) { vb.b[e] = (__bf16)b0[e]; vb.b[e + 4] = (__bf16)b1[e]; }
            }
            *(u32x4*)(sA + ((row * 128 + col8 * 16) ^ ((row & 7) << 4))) = va.u;
            *(u32x4*)(sB + ((row * 128 + col8 * 16) ^ ((row & 7) << 4))) = vb.u;
        }
        __syncthreads();
        #pragma unroll
        for (int kk = 0; kk < 2; ++kk) {
            V8 a[4], b[2];
            #pragma unroll
            for (int i = 0; i < 4; ++i) {
                int row = wm + i * 16 + l15;
                a[i].u = *(const u32x4*)(sA + ((row * 128 + kk * 64 + l4 * 16) ^ ((row & 7) << 4)));
            }
            #pragma unroll
            for (int j = 0; j < 2; ++j) {
                int col = wn + j * 16 + l15;
                b[j].u = *(const u32x4*)(sB + ((col * 128 + kk * 64 + l4 * 16) ^ ((col & 7) << 4)));
            }
            #pragma unroll
            for (int i = 0; i < 4; ++i)
                #pragma unroll
                for (int j = 0; j < 2; ++j)
                    acc[i][j] = __builtin_amdgcn_mfma_f32_16x16x32_bf16(a[i].b, b[j].b, acc[i][j], 0, 0, 0);
        }
    }

    #pragma unroll
    for (int i = 0; i < 4; ++i)
        #pragma unroll
        for (int j = 0; j < 2; ++j)
            #pragma unroll
            for (int r = 0; r < 4; ++r) {
                int rowg = bm + wm + i * 16 + l4 * 4 + r;
                int colg = bnl + wn + j * 16 + l15;
                if constexpr (OUT_F32)
                    ((float*)Cp)[(size_t)rowg * ldC + colg] = acc[i][j][r];
                else
                    ((ushort_t*)Cp)[(size_t)rowg * ldC + colg] = f2b(acc[i][j][r]);
            }
}

// ---------------------------------------------------------------------------
// Fused RMSNorm + RoPE (unchanged)
// ---------------------------------------------------------------------------
__global__ __launch_bounds__(256) void norm_rope(
    ushort_t* __restrict__ X, const float* __restrict__ W,
    const float* __restrict__ FC, const float* __restrict__ FS,
    int row_stride)
{
    const int t   = blockIdx.x;
    const int tid = threadIdx.x;
    const int h   = tid >> 4;
    const int sub = tid & 15;

    ushort_t* p = X + (size_t)t * row_stride + h * HD + sub * 8;
    V8 v; v.u = *(const u32x4*)p;
    float f[8];
    #pragma unroll
    for (int e = 0; e < 8; ++e) f[e] = b2f((ushort_t)v.s[e]);

    float ss = 0.f;
    #pragma unroll
    for (int e = 0; e < 8; ++e) ss += f[e] * f[e];
    ss += __shfl_xor(ss, 1);
    ss += __shfl_xor(ss, 2);
    ss += __shfl_xor(ss, 4);
    ss += __shfl_xor(ss, 8);
    float inv = rsqrtf(ss * (1.0f / 128.0f) + 1e-6f);

    float outv[8];
    #pragma unroll
    for (int k = 0; k < 4; ++k) {
        float c  = FC[(size_t)t * 64 + sub * 4 + k];
        float s  = FS[(size_t)t * 64 + sub * 4 + k];
        float w0 = W[sub * 8 + 2 * k];
        float w1 = W[sub * 8 + 2 * k + 1];
        float re = f[2 * k] * inv * w0;
        float im = f[2 * k + 1] * inv * w1;
        outv[2 * k]     = re * c - im * s;
        outv[2 * k + 1] = re * s + im * c;
    }
    V8 o;
    #pragma unroll
    for (int e = 0; e < 8; ++e) o.s[e] = (short)f2b(outv[e]);
    *(u32x4*)p = o.u;
}

// ---------------------------------------------------------------------------
// Causal flash attention, 8 waves (512 thr):
//  - group A (waves 0-3) = even kv-tiles, group B (waves 4-7) = odd kv-tiles,
//    same 64 q-rows; per-group online softmax; LDS merge at phase end.
//  - pair (p, 31-p) per block => 33 kv-tiles/block, 256 blocks, balanced.
//  - XCD swizzle: 2 heads per XCD so per-XCD KV working set fits L2.
// ---------------------------------------------------------------------------
#define STAGE_LOAD(kv0) do { \
  _Pragma("unroll") for (int rr = 0; rr < 4; ++rr) \
    kreg[rr] = *(const u32x4*)(KV + (size_t)((kv0) + krow[rr]) * (2 * DIM) + h * HD + kc8 * 8); \
  _Pragma("unroll") for (int rr = 0; rr < 2; ++rr) \
    _Pragma("unroll") for (int e = 0; e < 8; ++e) \
      vreg[rr][e] = *(const unsigned*)(KV + (size_t)((kv0) + vkvb[rr] * 8 + e) * (2 * DIM) + DIM + h * HD + vd); \
} while (0)

#define STAGE_WRITE(sKb, sVb) do { \
  _Pragma("unroll") for (int rr = 0; rr < 4; ++rr) \
    *(u32x4*)((sKb) + ((krow[rr] * 256 + kc8 * 16) ^ ((krow[rr] & 7) << 4))) = kreg[rr]; \
  _Pragma("unroll") for (int rr = 0; rr < 2; ++rr) { \
    V8 lo, hi; \
    _Pragma("unroll") for (int e = 0; e < 8; ++e) { \
      lo.s[e] = (short)(vreg[rr][e] & 0xFFFFu); hi.s[e] = (short)(vreg[rr][e] >> 16); } \
    *(u32x4*)((sVb) + ((vd * 128 + vkvb[rr] * 16) ^ ((vd & 7) << 4)))             = lo.u; \
    *(u32x4*)((sVb) + (((vd + 1) * 128 + vkvb[rr] * 16) ^ (((vd + 1) & 7) << 4))) = hi.u; \
  } \
} while (0)

__global__ __launch_bounds__(512) void attn_kernel(
    const ushort_t* __restrict__ Q,
    const ushort_t* __restrict__ KV,
    ushort_t* __restrict__ O)
{
    __shared__ __align__(16) char sAll[131072];

    const int id    = blockIdx.x;          // 0..255
    const int xcd   = id & 7;
    const int slot  = id >> 3;             // 0..31
    const int h     = xcd * 2 + (slot >> 4);
    const int pairb = slot & 15;

    const int tid   = threadIdx.x;
    const int gid   = tid >> 8;            // 0: even tiles, 1: odd tiles
    const int wtid  = tid & 255;
    const int wave4 = wtid >> 6;
    const int lane  = tid & 63;
    const int Qq    = lane & 15;
    const int G     = lane >> 4;

    char* gbase = sAll + gid * 65536;      // [K0 16K][K1 16K][V0 16K][V1 16K]

    const int krow[4] = { (0*256 + wtid) >> 4, (1*256 + wtid) >> 4,
                          (2*256 + wtid) >> 4, (3*256 + wtid) >> 4 };
    const int kc8 = wtid & 15;
    const int vd  = lane * 2;
    const int vkvb[2] = { wave4, 4 + wave4 };

    const float scale = 0.08838834764831845f;  // 1/sqrt(128)

    u32x4 kreg[4];
    unsigned vreg[2][8];

    #pragma unroll
    for (int phase = 0; phase < 2; ++phase) {
        const int jt  = phase ? (31 - pairb) : pairb;
        const int q0w = jt * 64 + wave4 * 16;

        V8 qf[4];
        #pragma unroll
        for (int kk = 0; kk < 4; ++kk)
            qf[kk].u = *(const u32x4*)(Q + (size_t)(q0w + Qq) * DIM + h * HD + kk * 32 + G * 8);

        f32x4 o[8] = {};
        float mrow = -1e30f, lrow = 0.f;

        const int n_g = (jt >= gid) ? ((jt - gid) >> 1) + 1 : 0;
        const int nA  = (jt >> 1) + 1;

        if (n_g > 0) {
            STAGE_LOAD(gid * 64);
            STAGE_WRITE(gbase, gbase + 32768);
        }

        int cur = 0;
        for (int s = 0; s < nA; ++s) {
            __syncthreads();

            const bool pf = (s + 1 < n_g);
            if (pf) STAGE_LOAD((2 * (s + 1) + gid) * 64);

            if (s < n_g) {
                const int tcur = 2 * s + gid;
                const int kv0  = tcur * 64;
                char* sKb = gbase + cur * 16384;
                char* sVb = gbase + 32768 + cur * 16384;

                // S^T = K Q^T : lane q = Qq, kv = cb*16 + G*4 + r
                f32x4 sacc[4] = {};
                #pragma unroll
                for (int kk = 0; kk < 4; ++kk) {
                    #pragma unroll
                    for (int cb = 0; cb < 4; ++cb) {
                        int row = cb * 16 + Qq;
                        V8 kf;
                        kf.u = *(const u32x4*)(sKb + ((row * 256 + kk * 64 + G * 16) ^ ((row & 7) << 4)));
                        sacc[cb] = __builtin_amdgcn_mfma_f32_16x16x32_bf16(kf.b, qf[kk].b, sacc[cb], 0, 0, 0);
                    }
                }

                // softmax (lane-local in q)
                float p[4][4];
                float tmax = -3e38f;
                const int qg = q0w + Qq;
                #pragma unroll
                for (int cb = 0; cb < 4; ++cb)
                    #pragma unroll
                    for (int r = 0; r < 4; ++r) {
                        float s2 = sacc[cb][r] * scale;
                        if (tcur == jt) {
                            int kvg = kv0 + cb * 16 + G * 4 + r;
                            if (kvg > qg) s2 = -1e30f;
                        }
                        p[cb][r] = s2;
                        tmax = fmaxf(tmax, s2);
                    }
                tmax = fmaxf(tmax, __shfl_xor(tmax, 16));
                tmax = fmaxf(tmax, __shfl_xor(tmax, 32));
                float mnew = fmaxf(mrow, tmax);
                float corr = __expf(mrow - mnew);
                mrow = mnew;
                float rs = 0.f;
                #pragma unroll
                for (int cb = 0; cb < 4; ++cb)
                    #pragma unroll
                    for (int r = 0; r < 4; ++r) {
                        float e = __expf(p[cb][r] - mnew);
                        p[cb][r] = e;
                        rs += e;
                    }
                rs += __shfl_xor(rs, 16);
                rs += __shfl_xor(rs, 32);
                lrow = lrow * corr + rs;

                unsigned pk[4][2];
                #pragma unroll
                for (int cb = 0; cb < 4; ++cb) {
                    pk[cb][0] = (unsigned)f2b(p[cb][0]) | ((unsigned)f2b(p[cb][1]) << 16);
                    pk[cb][1] = (unsigned)f2b(p[cb][2]) | ((unsigned)f2b(p[cb][3]) << 16);
                }

                float cf[4];
                #pragma unroll
                for (int r = 0; r < 4; ++r)
                    cf[r] = __shfl(corr, G * 4 + r);
                #pragma unroll
                for (int nb = 0; nb < 8; ++nb)
                    #pragma unroll
                    for (int r = 0; r < 4; ++r)
                        o[nb][r] *= cf[r];

                // O += P V (P A-fragment rebuilt in-register)
                const int sLo = ((G & 1) * 2) * 16 + Qq;
                const int sHi = sLo + 16;
                const bool hiC = (G >> 1);
                #pragma unroll
                for (int kk2 = 0; kk2 < 2; ++kk2) {
                    const int c0 = kk2 * 2, c1 = c0 + 1;
                    unsigned w0a = __shfl(pk[c0][0], sLo), w0b = __shfl(pk[c1][0], sLo);
                    unsigned w1a = __shfl(pk[c0][1], sLo), w1b = __shfl(pk[c1][1], sLo);
                    unsigned w2a = __shfl(pk[c0][0], sHi), w2b = __shfl(pk[c1][0], sHi);
                    unsigned w3a = __shfl(pk[c0][1], sHi), w3b = __shfl(pk[c1][1], sHi);
                    V8 pa;
                    pa.u[0] = hiC ? w0b : w0a;
                    pa.u[1] = hiC ? w1b : w1a;
                    pa.u[2] = hiC ? w2b : w2a;
                    pa.u[3] = hiC ? w3b : w3a;
                    #pragma unroll
                    for (int nb = 0; nb < 8; ++nb) {
                        int d = nb * 16 + Qq;
                        V8 vf;
                        vf.u = *(const u32x4*)(sVb + ((d * 128 + kk2 * 64 + G * 16) ^ ((d & 7) << 4)));
                        o[nb] = __builtin_amdgcn_mfma_f32_16x16x32_bf16(pa.b, vf.b, o[nb], 0, 0, 0);
                    }
                }
            }

            if (pf) STAGE_WRITE(gbase + (cur ^ 1) * 16384, gbase + 32768 + (cur ^ 1) * 16384);
            cur ^= 1;
        }

        // ---- merge group B into group A ----
        __syncthreads();   // all compute done; LDS reusable
        float* mrg = (float*)sAll;               // [64 q][132 words] f32
        float* mlb = (float*)(sAll + 33792);     // [m:64][l:64]
        if (gid == 1) {
            #pragma unroll
            for (int nb = 0; nb < 8; ++nb)
                #pragma unroll
                for (int r = 0; r < 4; ++r) {
                    int qloc = wave4 * 16 + G * 4 + r;
                    mrg[qloc * 132 + nb * 16 + Qq] = o[nb][r];
                }
            if (G == 0) {
                int qloc = wave4 * 16 + Qq;
                mlb[qloc]      = mrow;
                mlb[64 + qloc] = lrow;
            }
        }
        __syncthreads();
        if (gid == 0) {
            int qloc0 = wave4 * 16 + Qq;
            float mB = mlb[qloc0], lB = mlb[64 + qloc0];
            float m  = fmaxf(mrow, mB);
            float cA = __expf(mrow - m), cB = __expf(mB - m);
            float linv = 1.f / (lrow * cA + lB * cB);
            float cAr[4], cBr[4], lir[4];
            #pragma unroll
            for (int r = 0; r < 4; ++r) {
                cAr[r] = __shfl(cA, G * 4 + r);
                cBr[r] = __shfl(cB, G * 4 + r);
                lir[r] = __shfl(linv, G * 4 + r);
            }
            #pragma unroll
            for (int nb = 0; nb < 8; ++nb)
                #pragma unroll
                for (int r = 0; r < 4; ++r) {
                    int qloc = wave4 * 16 + G * 4 + r;
                    float ob  = mrg[qloc * 132 + nb * 16 + Qq];
                    float val = (o[nb][r] * cAr[r] + ob * cBr[r]) * lir[r];
                    int qgr = jt * 64 + qloc;
                    O[(size_t)qgr * DIM + h * HD + nb * 16 + Qq] = f2b(val);
                }
        }
        __syncthreads();   // phase seam
    }
}

// ---------------------------------------------------------------------------
extern "C" void kernel_launch(void* const* d_in, const int* in_sizes, int n_in,
                              void* d_out, int out_size, void* d_ws, size_t ws_size,
                              hipStream_t stream)
{
    const float* x    = (const float*)d_in[0];
    const float* wq   = (const float*)d_in[1];
    const float* wkvd = (const float*)d_in[2];
    const float* wkvu = (const float*)d_in[3];
    const float* wo   = (const float*)d_in[4];
    const float* qnw  = (const float*)d_in[5];
    const float* knw  = (const float*)d_in[6];
    const float* fc   = (const float*)d_in[7];
    const float* fs   = (const float*)d_in[8];
    float* out = (float*)d_out;

    char* ws = (char*)d_ws;
    ushort_t* Qb  = (ushort_t*)(ws);                             // 2048*2048 bf16 = 8 MB
    ushort_t* lat = (ushort_t*)(ws + (size_t)8  * 1024 * 1024);  // 2048*512       = 2 MB
    ushort_t* kv  = (ushort_t*)(ws + (size_t)10 * 1024 * 1024);  // 2048*4096      = 16 MB
    ushort_t* att = (ushort_t*)(ws + (size_t)26 * 1024 * 1024);  // 2048*2048      = 8 MB

    dim3 blk(512);
    // fused: xq = x.wq^T (cols 0..2047 -> Qb) and latent = x.w_kv_down^T (cols 2048..2559 -> lat)
    gemm_nt<false, false><<<dim3(16, 20), blk, 0, stream>>>(x, wq, Qb, 2048, 2048,
                                                            wkvd, lat, 2048, 512);
    // kv = latent . w_kv_up^T
    gemm_nt<true, false><<<dim3(16, 32), blk, 0, stream>>>(lat, wkvu, kv, 2048, 512,
                                                           nullptr, nullptr, 4096, 0);
    norm_rope<<<dim3(2048), dim3(256), 0, stream>>>(Qb, qnw, fc, fs, 2048);
    norm_rope<<<dim3(2048), dim3(256), 0, stream>>>(kv, knw, fc, fs, 4096);
    attn_kernel<<<dim3(256), blk, 0, stream>>>(Qb, kv, att);
    // y = att . wo^T
    gemm_nt<true, true><<<dim3(16, 16), blk, 0, stream>>>(att, wo, out, 2048, 2048,
                                                          nullptr, nullptr, 2048, 0);
}

// Round 5
// 171.165 us; speedup vs baseline: 2.2922x; 1.1547x over previous
//
#include <hip/hip_runtime.h>

#define T_SEQ 2048
#define DIM   2048
#define NH    16
#define HD    128
#define KVR   512

typedef unsigned short ushort_t;
typedef __attribute__((ext_vector_type(8))) short   short8;
typedef __attribute__((ext_vector_type(8))) __bf16  bf16x8;
typedef __attribute__((ext_vector_type(4))) float   f32x4;
typedef __attribute__((ext_vector_type(4))) unsigned int u32x4;

union V8 { short8 s; bf16x8 b; u32x4 u; };

__device__ inline float b2f(ushort_t u) {
    union { unsigned u; float f; } x; x.u = ((unsigned)u) << 16; return x.f;
}
__device__ inline ushort_t f2b(float f) {
    union { float f; unsigned u; } x; x.f = f;
    unsigned r = x.u + 0x7FFFu + ((x.u >> 16) & 1u);
    return (ushort_t)(r >> 16);
}

__device__ __forceinline__ void gld16(char* lds, const ushort_t* g) {
    __builtin_amdgcn_global_load_lds(
        (const __attribute__((address_space(1))) unsigned int*)g,
        (__attribute__((address_space(3))) unsigned int*)lds,
        16, 0, 0);
}

// ---------------------------------------------------------------------------
// Batched f32 -> bf16 conversion of x, wq, w_kv_down, w_kv_up, wo.
// Chunk = 8 elements. Sizes compile-time for this problem.
// ---------------------------------------------------------------------------
__global__ __launch_bounds__(256) void cvtk(
    const float* __restrict__ a0, const float* __restrict__ a1,
    const float* __restrict__ a2, const float* __restrict__ a3,
    const float* __restrict__ a4,
    ushort_t* __restrict__ b0, ushort_t* __restrict__ b1,
    ushort_t* __restrict__ b2, ushort_t* __restrict__ b3,
    ushort_t* __restrict__ b4)
{
    const int N0 = 524288, N1 = 1048576, N2 = 1179648, N3 = 1441792, N4 = 1966080;
    for (int c = blockIdx.x * blockDim.x + threadIdx.x; c < N4; c += gridDim.x * blockDim.x) {
        const float* s; ushort_t* d; int off;
        if      (c < N0) { s = a0; d = b0; off = c; }
        else if (c < N1) { s = a1; d = b1; off = c - N0; }
        else if (c < N2) { s = a2; d = b2; off = c - N1; }
        else if (c < N3) { s = a3; d = b3; off = c - N2; }
        else             { s = a4; d = b4; off = c - N3; }
        f32x4 lo = *(const f32x4*)(s + (size_t)off * 8);
        f32x4 hi = *(const f32x4*)(s + (size_t)off * 8 + 4);
        V8 v;
        #pragma unroll
        for (int e = 0; e < 4; ++e) { v.b[e] = (__bf16)lo[e]; v.b[e + 4] = (__bf16)hi[e]; }
        *(u32x4*)(d + (size_t)off * 8) = v.u;
    }
}

// ---------------------------------------------------------------------------
// NT GEMM, all-bf16 inputs: C[m,n] = sum_k A[m,k]*B[n,k].
// 128x128 tile, BK=64, 256 thr / 4 waves (64x64 each). Double-buffered
// global_load_lds staging (issue-after-barrier -> overlaps compute), LDS
// swizzle realized via inverse-permuted global source (XOR involution).
// Optional fused second output for bn >= Nsplit (B2/C2, ldC=N2).
// ---------------------------------------------------------------------------
template <bool OUT_F32>
__global__ __launch_bounds__(256) void gemm_nt(
    const ushort_t* __restrict__ A, const ushort_t* __restrict__ B,
    void* __restrict__ Cv, int M, int K,
    const ushort_t* __restrict__ B2, void* __restrict__ C2, int Nsplit, int N2)
{
    __shared__ __align__(16) char sA[2][16384];
    __shared__ __align__(16) char sB[2][16384];

    const int tid  = threadIdx.x;
    const int wave = tid >> 6;
    const int lane = tid & 63;
    const int l15  = lane & 15;
    const int l4   = lane >> 4;
    const int bm   = blockIdx.x * 128;
    const int bn   = blockIdx.y * 128;

    const ushort_t* Bp = B;
    void* Cp = Cv; int ldC = Nsplit; int bnl = bn;
    if (B2 != nullptr && bn >= Nsplit) { Bp = B2; Cp = C2; ldC = N2; bnl = bn - Nsplit; }

    const int wm = (wave >> 1) * 64;
    const int wn = (wave & 1) * 64;

    // staging source: lane-permuted so linear LDS dest ends up XOR-swizzled
    const int lp   = lane ^ ((lane >> 3) & 7);   // involution on 16B-chunk idx
    const int prow = lp >> 3;
    const int psub = lp & 7;
    const ushort_t* aSrc[4];
    const ushort_t* bSrc[4];
    #pragma unroll
    for (int i = 0; i < 4; ++i) {
        int r = wave * 32 + i * 8 + prow;        // 4 waves x 4 calls x 8 rows = 128
        aSrc[i] = A  + (size_t)(bm  + r) * K + psub * 8;
        bSrc[i] = Bp + (size_t)(bnl + r) * K + psub * 8;
    }
    const int ldsOff = wave * 4096;              // bytes

    f32x4 acc[4][4] = {};
    const int nk = K >> 6;

    #pragma unroll
    for (int i = 0; i < 4; ++i) {
        gld16(&sA[0][ldsOff + i * 1024], aSrc[i]);
        gld16(&sB[0][ldsOff + i * 1024], bSrc[i]);
    }

    int cur = 0;
    for (int k = 0; k < nk; ++k) {
        __syncthreads();   // compiler drain: tile k landed, prior reads done
        if (k + 1 < nk) {
            const int ko = (k + 1) * 64;
            #pragma unroll
            for (int i = 0; i < 4; ++i) {
                gld16(&sA[cur ^ 1][ldsOff + i * 1024], aSrc[i] + ko);
                gld16(&sB[cur ^ 1][ldsOff + i * 1024], bSrc[i] + ko);
            }
        }
        #pragma unroll
        for (int kk = 0; kk < 2; ++kk) {
            V8 a[4], b[4];
            #pragma unroll
            for (int i2 = 0; i2 < 4; ++i2) {
                int row = wm + i2 * 16 + l15;
                a[i2].u = *(const u32x4*)(sA[cur] + ((row * 128 + kk * 64 + l4 * 16) ^ ((row & 7) << 4)));
                int col = wn + i2 * 16 + l15;
                b[i2].u = *(const u32x4*)(sB[cur] + ((col * 128 + kk * 64 + l4 * 16) ^ ((col & 7) << 4)));
            }
            #pragma unroll
            for (int i2 = 0; i2 < 4; ++i2)
                #pragma unroll
                for (int j = 0; j < 4; ++j)
                    acc[i2][j] = __builtin_amdgcn_mfma_f32_16x16x32_bf16(a[i2].b, b[j].b, acc[i2][j], 0, 0, 0);
        }
        cur ^= 1;
    }

    #pragma unroll
    for (int i = 0; i < 4; ++i)
        #pragma unroll
        for (int j = 0; j < 4; ++j)
            #pragma unroll
            for (int r = 0; r < 4; ++r) {
                int rowg = bm + wm + i * 16 + l4 * 4 + r;
                int colg = bnl + wn + j * 16 + l15;
                if constexpr (OUT_F32)
                    ((float*)Cp)[(size_t)rowg * ldC + colg] = acc[i][j][r];
                else
                    ((ushort_t*)Cp)[(size_t)rowg * ldC + colg] = f2b(acc[i][j][r]);
            }
}

// ---------------------------------------------------------------------------
// Fused RMSNorm + RoPE for Q and K in one launch (grid 4096).
// ---------------------------------------------------------------------------
__global__ __launch_bounds__(256) void norm_rope2(
    ushort_t* __restrict__ Qb, ushort_t* __restrict__ KVb,
    const float* __restrict__ QW, const float* __restrict__ KW,
    const float* __restrict__ FC, const float* __restrict__ FS)
{
    const int b    = blockIdx.x;
    const bool isK = b >= 2048;
    const int t    = b & 2047;
    const int tid  = threadIdx.x;
    const int h    = tid >> 4;
    const int sub  = tid & 15;

    ushort_t* X        = isK ? KVb : Qb;
    const float* W     = isK ? KW : QW;
    const int stride   = isK ? 4096 : 2048;

    ushort_t* p = X + (size_t)t * stride + h * HD + sub * 8;
    V8 v; v.u = *(const u32x4*)p;
    float f[8];
    #pragma unroll
    for (int e = 0; e < 8; ++e) f[e] = b2f((ushort_t)v.s[e]);

    float ss = 0.f;
    #pragma unroll
    for (int e = 0; e < 8; ++e) ss += f[e] * f[e];
    ss += __shfl_xor(ss, 1);
    ss += __shfl_xor(ss, 2);
    ss += __shfl_xor(ss, 4);
    ss += __shfl_xor(ss, 8);
    float inv = rsqrtf(ss * (1.0f / 128.0f) + 1e-6f);

    float outv[8];
    #pragma unroll
    for (int k = 0; k < 4; ++k) {
        float c  = FC[(size_t)t * 64 + sub * 4 + k];
        float s  = FS[(size_t)t * 64 + sub * 4 + k];
        float w0 = W[sub * 8 + 2 * k];
        float w1 = W[sub * 8 + 2 * k + 1];
        float re = f[2 * k] * inv * w0;
        float im = f[2 * k + 1] * inv * w1;
        outv[2 * k]     = re * c - im * s;
        outv[2 * k + 1] = re * s + im * c;
    }
    V8 o;
    #pragma unroll
    for (int e = 0; e < 8; ++e) o.s[e] = (short)f2b(outv[e]);
    *(u32x4*)p = o.u;
}

// ---------------------------------------------------------------------------
// Causal flash attention (unchanged from round 4).
// ---------------------------------------------------------------------------
#define STAGE_LOAD(kv0) do { \
  _Pragma("unroll") for (int rr = 0; rr < 4; ++rr) \
    kreg[rr] = *(const u32x4*)(KV + (size_t)((kv0) + krow[rr]) * (2 * DIM) + h * HD + kc8 * 8); \
  _Pragma("unroll") for (int rr = 0; rr < 2; ++rr) \
    _Pragma("unroll") for (int e = 0; e < 8; ++e) \
      vreg[rr][e] = *(const unsigned*)(KV + (size_t)((kv0) + vkvb[rr] * 8 + e) * (2 * DIM) + DIM + h * HD + vd); \
} while (0)

#define STAGE_WRITE(sKb, sVb) do { \
  _Pragma("unroll") for (int rr = 0; rr < 4; ++rr) \
    *(u32x4*)((sKb) + ((krow[rr] * 256 + kc8 * 16) ^ ((krow[rr] & 7) << 4))) = kreg[rr]; \
  _Pragma("unroll") for (int rr = 0; rr < 2; ++rr) { \
    V8 lo, hi; \
    _Pragma("unroll") for (int e = 0; e < 8; ++e) { \
      lo.s[e] = (short)(vreg[rr][e] & 0xFFFFu); hi.s[e] = (short)(vreg[rr][e] >> 16); } \
    *(u32x4*)((sVb) + ((vd * 128 + vkvb[rr] * 16) ^ ((vd & 7) << 4)))             = lo.u; \
    *(u32x4*)((sVb) + (((vd + 1) * 128 + vkvb[rr] * 16) ^ (((vd + 1) & 7) << 4))) = hi.u; \
  } \
} while (0)

__global__ __launch_bounds__(512) void attn_kernel(
    const ushort_t* __restrict__ Q,
    const ushort_t* __restrict__ KV,
    ushort_t* __restrict__ O)
{
    __shared__ __align__(16) char sAll[131072];

    const int id    = blockIdx.x;
    const int xcd   = id & 7;
    const int slot  = id >> 3;
    const int h     = xcd * 2 + (slot >> 4);
    const int pairb = slot & 15;

    const int tid   = threadIdx.x;
    const int gid   = tid >> 8;
    const int wtid  = tid & 255;
    const int wave4 = wtid >> 6;
    const int lane  = tid & 63;
    const int Qq    = lane & 15;
    const int G     = lane >> 4;

    char* gbase = sAll + gid * 65536;

    const int krow[4] = { (0*256 + wtid) >> 4, (1*256 + wtid) >> 4,
                          (2*256 + wtid) >> 4, (3*256 + wtid) >> 4 };
    const int kc8 = wtid & 15;
    const int vd  = lane * 2;
    const int vkvb[2] = { wave4, 4 + wave4 };

    const float scale = 0.08838834764831845f;

    u32x4 kreg[4];
    unsigned vreg[2][8];

    #pragma unroll
    for (int phase = 0; phase < 2; ++phase) {
        const int jt  = phase ? (31 - pairb) : pairb;
        const int q0w = jt * 64 + wave4 * 16;

        V8 qf[4];
        #pragma unroll
        for (int kk = 0; kk < 4; ++kk)
            qf[kk].u = *(const u32x4*)(Q + (size_t)(q0w + Qq) * DIM + h * HD + kk * 32 + G * 8);

        f32x4 o[8] = {};
        float mrow = -1e30f, lrow = 0.f;

        const int n_g = (jt >= gid) ? ((jt - gid) >> 1) + 1 : 0;
        const int nA  = (jt >> 1) + 1;

        if (n_g > 0) {
            STAGE_LOAD(gid * 64);
            STAGE_WRITE(gbase, gbase + 32768);
        }

        int cur = 0;
        for (int s = 0; s < nA; ++s) {
            __syncthreads();

            const bool pf = (s + 1 < n_g);
            if (pf) STAGE_LOAD((2 * (s + 1) + gid) * 64);

            if (s < n_g) {
                const int tcur = 2 * s + gid;
                const int kv0  = tcur * 64;
                char* sKb = gbase + cur * 16384;
                char* sVb = gbase + 32768 + cur * 16384;

                f32x4 sacc[4] = {};
                #pragma unroll
                for (int kk = 0; kk < 4; ++kk) {
                    #pragma unroll
                    for (int cb = 0; cb < 4; ++cb) {
                        int row = cb * 16 + Qq;
                        V8 kf;
                        kf.u = *(const u32x4*)(sKb + ((row * 256 + kk * 64 + G * 16) ^ ((row & 7) << 4)));
                        sacc[cb] = __builtin_amdgcn_mfma_f32_16x16x32_bf16(kf.b, qf[kk].b, sacc[cb], 0, 0, 0);
                    }
                }

                float p[4][4];
                float tmax = -3e38f;
                const int qg = q0w + Qq;
                #pragma unroll
                for (int cb = 0; cb < 4; ++cb)
                    #pragma unroll
                    for (int r = 0; r < 4; ++r) {
                        float s2 = sacc[cb][r] * scale;
                        if (tcur == jt) {
                            int kvg = kv0 + cb * 16 + G * 4 + r;
                            if (kvg > qg) s2 = -1e30f;
                        }
                        p[cb][r] = s2;
                        tmax = fmaxf(tmax, s2);
                    }
                tmax = fmaxf(tmax, __shfl_xor(tmax, 16));
                tmax = fmaxf(tmax, __shfl_xor(tmax, 32));
                float mnew = fmaxf(mrow, tmax);
                float corr = __expf(mrow - mnew);
                mrow = mnew;
                float rs = 0.f;
                #pragma unroll
                for (int cb = 0; cb < 4; ++cb)
                    #pragma unroll
                    for (int r = 0; r < 4; ++r) {
                        float e = __expf(p[cb][r] - mnew);
                        p[cb][r] = e;
                        rs += e;
                    }
                rs += __shfl_xor(rs, 16);
                rs += __shfl_xor(rs, 32);
                lrow = lrow * corr + rs;

                unsigned pk[4][2];
                #pragma unroll
                for (int cb = 0; cb < 4; ++cb) {
                    pk[cb][0] = (unsigned)f2b(p[cb][0]) | ((unsigned)f2b(p[cb][1]) << 16);
                    pk[cb][1] = (unsigned)f2b(p[cb][2]) | ((unsigned)f2b(p[cb][3]) << 16);
                }

                float cf[4];
                #pragma unroll
                for (int r = 0; r < 4; ++r)
                    cf[r] = __shfl(corr, G * 4 + r);
                #pragma unroll
                for (int nb = 0; nb < 8; ++nb)
                    #pragma unroll
                    for (int r = 0; r < 4; ++r)
                        o[nb][r] *= cf[r];

                const int sLo = ((G & 1) * 2) * 16 + Qq;
                const int sHi = sLo + 16;
                const bool hiC = (G >> 1);
                #pragma unroll
                for (int kk2 = 0; kk2 < 2; ++kk2) {
                    const int c0 = kk2 * 2, c1 = c0 + 1;
                    unsigned w0a = __shfl(pk[c0][0], sLo), w0b = __shfl(pk[c1][0], sLo);
                    unsigned w1a = __shfl(pk[c0][1], sLo), w1b = __shfl(pk[c1][1], sLo);
                    unsigned w2a = __shfl(pk[c0][0], sHi), w2b = __shfl(pk[c1][0], sHi);
                    unsigned w3a = __shfl(pk[c0][1], sHi), w3b = __shfl(pk[c1][1], sHi);
                    V8 pa;
                    pa.u[0] = hiC ? w0b : w0a;
                    pa.u[1] = hiC ? w1b : w1a;
                    pa.u[2] = hiC ? w2b : w2a;
                    pa.u[3] = hiC ? w3b : w3a;
                    #pragma unroll
                    for (int nb = 0; nb < 8; ++nb) {
                        int d = nb * 16 + Qq;
                        V8 vf;
                        vf.u = *(const u32x4*)(sVb + ((d * 128 + kk2 * 64 + G * 16) ^ ((d & 7) << 4)));
                        o[nb] = __builtin_amdgcn_mfma_f32_16x16x32_bf16(pa.b, vf.b, o[nb], 0, 0, 0);
                    }
                }
            }

            if (pf) STAGE_WRITE(gbase + (cur ^ 1) * 16384, gbase + 32768 + (cur ^ 1) * 16384);
            cur ^= 1;
        }

        __syncthreads();
        float* mrg = (float*)sAll;
        float* mlb = (float*)(sAll + 33792);
        if (gid == 1) {
            #pragma unroll
            for (int nb = 0; nb < 8; ++nb)
                #pragma unroll
                for (int r = 0; r < 4; ++r) {
                    int qloc = wave4 * 16 + G * 4 + r;
                    mrg[qloc * 132 + nb * 16 + Qq] = o[nb][r];
                }
            if (G == 0) {
                int qloc = wave4 * 16 + Qq;
                mlb[qloc]      = mrow;
                mlb[64 + qloc] = lrow;
            }
        }
        __syncthreads();
        if (gid == 0) {
            int qloc0 = wave4 * 16 + Qq;
            float mB = mlb[qloc0], lB = mlb[64 + qloc0];
            float m  = fmaxf(mrow, mB);
            float cA = __expf(mrow - m), cB = __expf(mB - m);
            float linv = 1.f / (lrow * cA + lB * cB);
            float cAr[4], cBr[4], lir[4];
            #pragma unroll
            for (int r = 0; r < 4; ++r) {
                cAr[r] = __shfl(cA, G * 4 + r);
                cBr[r] = __shfl(cB, G * 4 + r);
                lir[r] = __shfl(linv, G * 4 + r);
            }
            #pragma unroll
            for (int nb = 0; nb < 8; ++nb)
                #pragma unroll
                for (int r = 0; r < 4; ++r) {
                    int qloc = wave4 * 16 + G * 4 + r;
                    float ob  = mrg[qloc * 132 + nb * 16 + Qq];
                    float val = (o[nb][r] * cAr[r] + ob * cBr[r]) * lir[r];
                    int qgr = jt * 64 + qloc;
                    O[(size_t)qgr * DIM + h * HD + nb * 16 + Qq] = f2b(val);
                }
        }
        __syncthreads();
    }
}

// ---------------------------------------------------------------------------
extern "C" void kernel_launch(void* const* d_in, const int* in_sizes, int n_in,
                              void* d_out, int out_size, void* d_ws, size_t ws_size,
                              hipStream_t stream)
{
    const float* x    = (const float*)d_in[0];
    const float* wq   = (const float*)d_in[1];
    const float* wkvd = (const float*)d_in[2];
    const float* wkvu = (const float*)d_in[3];
    const float* wo   = (const float*)d_in[4];
    const float* qnw  = (const float*)d_in[5];
    const float* knw  = (const float*)d_in[6];
    const float* fc   = (const float*)d_in[7];
    const float* fs   = (const float*)d_in[8];
    float* out = (float*)d_out;

    char* ws = (char*)d_ws;
    const size_t MB = 1024 * 1024;
    // region plan (46 MB): [0,8): xb then att; [8,16): Qb; [16,32): wqb+wkvdb then kv;
    // [32,34): lat; [34,38): wkvub; [38,46): wob
    ushort_t* xb    = (ushort_t*)(ws);
    ushort_t* att   = (ushort_t*)(ws);            // alias: xb dead after QKV gemm
    ushort_t* Qb    = (ushort_t*)(ws + 8  * MB);
    ushort_t* wqb   = (ushort_t*)(ws + 16 * MB);
    ushort_t* wkvdb = (ushort_t*)(ws + 24 * MB);
    ushort_t* kvb   = (ushort_t*)(ws + 16 * MB);  // alias: weights dead after QKV gemm
    ushort_t* lat   = (ushort_t*)(ws + 32 * MB);
    ushort_t* wkvub = (ushort_t*)(ws + 34 * MB);
    ushort_t* wob   = (ushort_t*)(ws + 38 * MB);

    // 1. convert all f32 operands to bf16
    cvtk<<<dim3(2048), dim3(256), 0, stream>>>(x, wq, wkvd, wkvu, wo,
                                               xb, wqb, wkvdb, wkvub, wob);
    // 2. fused: xq = x.wq^T (cols 0..2047) and latent = x.w_kv_down^T (cols 2048..2559)
    gemm_nt<false><<<dim3(16, 20), dim3(256), 0, stream>>>(xb, wqb, Qb, 2048, 2048,
                                                           wkvdb, lat, 2048, 512);
    // 3. kv = latent . w_kv_up^T
    gemm_nt<false><<<dim3(16, 32), dim3(256), 0, stream>>>(lat, wkvub, kvb, 2048, 512,
                                                           nullptr, nullptr, 4096, 0);
    // 4. rmsnorm + rope on Q and K (one launch)
    norm_rope2<<<dim3(4096), dim3(256), 0, stream>>>(Qb, kvb, qnw, knw, fc, fs);
    // 5. causal flash attention
    attn_kernel<<<dim3(256), dim3(512), 0, stream>>>(Qb, kvb, att);
    // 6. y = att . wo^T  (f32 out)
    gemm_nt<true><<<dim3(16, 16), dim3(256), 0, stream>>>(att, wob, out, 2048, 2048,
                                                          nullptr, nullptr, 2048, 0);
}